// Round 13
// baseline (110.831 us; speedup 1.0000x reference)
//
#include <hip/hip_runtime.h>
#include <hip/hip_bf16.h>

// Problem constants
#define B_   32
#define N_   2048
#define E_   768
#define OUT_ 384
#define HID_ 16
constexpr int ROWS   = B_ * N_;      // 65536
constexpr int TILE_M = 16;           // rows per tile
constexpr int TPB    = 8;            // tiles per block (persistent)
constexpr int NT     = OUT_ / 16;    // 24 N-tiles of local GEMM
constexpr int KT_L   = 6;            // 6 K-steps (local, K=192)
constexpr int KT_G   = 24;           // 24 K-steps (gate, K=768)
constexpr int S_AL   = 200;          // al row stride in shorts (400B: 16B-aligned, bank-spread)
constexpr int S_PL   = 392;          // pooled row stride in shorts
constexpr int XS_W   = 772;          // xs row stride in floats (3088B: 16B-aligned, bank-spread)

typedef __attribute__((ext_vector_type(8))) short bf16x8;
typedef __attribute__((ext_vector_type(4))) float f32x4;

__device__ __forceinline__ short f2bf(float f) {
  __hip_bfloat16 h = __float2bfloat16(f);          // RNE hardware cvt
  return __builtin_bit_cast(short, h);
}
__device__ __forceinline__ float bf2f(short s) {
  union { unsigned u; float f; } v; v.u = ((unsigned)(unsigned short)s) << 16;
  return v.f;
}

// deep async L2 load: issued where placed, cannot be sunk by the compiler
__device__ __forceinline__ void gload_frag(bf16x8& d, const short* a) {
  asm volatile("global_load_dwordx4 %0, %1, off" : "=&v"(d) : "v"(a));
}
#define WAITV(n) do { asm volatile("s_waitcnt vmcnt(" #n ")" ::: "memory"); \
                      __builtin_amdgcn_sched_barrier(0); } while (0)

// Abramowitz-Stegun 7.1.26, |err| <= 1.5e-7, branch-free
__device__ __forceinline__ float fast_erf(float x) {
  const float ax = __builtin_fabsf(x);
  const float t  = __builtin_amdgcn_rcpf(__builtin_fmaf(0.3275911f, ax, 1.0f));
  float p = __builtin_fmaf(1.061405429f, t, -1.453152027f);
  p = __builtin_fmaf(p, t, 1.421413741f);
  p = __builtin_fmaf(p, t, -0.284496736f);
  p = __builtin_fmaf(p, t, 0.254829592f);
  const float e = __expf(-ax * ax);
  const float y = __builtin_fmaf(-p * t, e, 1.0f);
  return __builtin_copysignf(y, x);
}
__device__ __forceinline__ float gelu(float v) {
  return 0.5f * v * (1.0f + fast_erf(v * 0.70710678118654752f));
}

// ---------------- pre-pass: build bf16 MFMA B-fragments in workspace ----------------
__global__ void prep_kernel(const float* __restrict__ w_l, const float* __restrict__ w_g1,
                            short* __restrict__ wsL, short* __restrict__ wsG) {
  int t = blockIdx.x * blockDim.x + threadIdx.x;
  int wave = t >> 6, ln = t & 63;
  int kg = ln >> 4, c16 = ln & 15;
  if (wave < NT * KT_L) {
    int n = wave / KT_L, ks = wave % KT_L;
    bf16x8 v;
#pragma unroll
    for (int j = 0; j < 8; ++j) {
      int k = ks * 32 + kg * 8 + j;
      v[j] = f2bf(w_l[k * OUT_ + n * 16 + c16]);
    }
    *reinterpret_cast<bf16x8*>(&wsL[(size_t)(wave * 64 + ln) * 8]) = v;
  } else if (wave < NT * KT_L + KT_G) {
    int ks = wave - NT * KT_L;
    bf16x8 v;
#pragma unroll
    for (int j = 0; j < 8; ++j) {
      int k = ks * 32 + kg * 8 + j;
      v[j] = f2bf(w_g1[k * HID_ + c16]);
    }
    *reinterpret_cast<bf16x8*>(&wsG[(size_t)(ks * 64 + ln) * 8]) = v;
  }
}

// ---------------- main fused kernel: 256 threads = 4 waves, persistent over 8 tiles ----------------
// x staged tile-by-tile via global_load_lds (in-flight bytes live in LDS, not VGPRs);
// single xs buffer: gate is the only consumer, so stage(t+1) overlaps local GEMM + epilogue of t.
template <bool USE_WS>
__global__ __launch_bounds__(256, 2)
void spectre_kernel(const float* __restrict__ x,
                    const float* __restrict__ w_g1, const float* __restrict__ b_g1,
                    const float* __restrict__ ln_g_w, const float* __restrict__ ln_g_b,
                    const float* __restrict__ w_g2, const float* __restrict__ b_g2,
                    const float* __restrict__ w_l, const float* __restrict__ b_l,
                    const float* __restrict__ ln_l_w, const float* __restrict__ ln_l_b,
                    const short* __restrict__ wsL, const short* __restrict__ wsG,
                    float* __restrict__ out) {
  __shared__ float xs[TILE_M][XS_W];     // 49408 B: x tile f32
  __shared__ short al[TILE_M * S_AL];    // 6400 B : local A (x[..., ::4] bf16), [row][local_k]
  __shared__ short pl[TILE_M * S_PL];    // 12544 B: pooled (bf16), [row][out_col]
  __shared__ float red2[4][16][17];      // 4352 B : gate partial sums per wave
  __shared__ float reds[4][16][2];       // 512 B  : local LN partials per wave
  // total 73216 B -> 2 blocks/CU

  const int tid = threadIdx.x;
  const int wv  = tid >> 6;        // wave 0..3
  const int ln  = tid & 63;        // lane
  const int kg  = ln >> 4;         // k-group / D-row group
  const int l15 = ln & 15;         // A-row / D-col

  // ---- hoisted per-block invariants ----
  bf16x8 gbv[6];
  if constexpr (USE_WS) {
#pragma unroll
    for (int i = 0; i < 6; ++i)
      gbv[i] = *reinterpret_cast<const bf16x8*>(&wsG[((wv * 6 + i) * 64 + ln) * 8]);
  }
  const float bg  = b_g1[l15];
  const float lgw = ln_g_w[l15];
  const float lgb = ln_g_b[l15];
  const float wg2 = w_g2[l15];
  const float bg2 = b_g2[0];
  float blv[6], lwv[6], lbv[6];
#pragma unroll
  for (int j = 0; j < 6; ++j) {
    const int col = (wv * 6 + j) * 16 + l15;
    blv[j] = b_l[col];
    lwv[j] = ln_l_w[col];
    lbv[j] = ln_l_b[col];
  }
  const short* wlp = USE_WS ? (wsL + ((size_t)(wv * 6) * KT_L * 64 + ln) * 8) : nullptr;

  // ---- stage helper: 12 global_load_lds per wave (4 rows x 3 KB) ----
  auto stage = [&](int t) {
    const float* src = x + (size_t)(blockIdx.x * TPB + t) * TILE_M * E_;
#pragma unroll
    for (int rr = 0; rr < 4; ++rr) {
      const int row = wv * 4 + rr;
#pragma unroll
      for (int c = 0; c < 3; ++c) {
        __builtin_amdgcn_global_load_lds(
            (const __attribute__((address_space(1))) void*)(src + row * E_ + c * 256 + ln * 4),
            (__attribute__((address_space(3))) void*)(&xs[row][c * 256]),
            16, 0, 0);
      }
    }
  };

  // ---- prologue: stage tile 0 ----
  stage(0);
  asm volatile("s_waitcnt vmcnt(0)" ::: "memory");
  __syncthreads();

  for (int t = 0; t < TPB; ++t) {
    const size_t rowg0 = (size_t)(blockIdx.x * TPB + t) * TILE_M;

    // ---- gate GEMM partial (wave wv: K-steps [6wv,6wv+6)); al/pl extracted inline ----
    f32x4 accg = {0.f, 0.f, 0.f, 0.f};
#pragma unroll
    for (int i = 0; i < 6; ++i) {
      const int ks = wv * 6 + i;
      const float4 u0 = *reinterpret_cast<const float4*>(&xs[l15][ks * 32 + kg * 8]);
      const float4 u1 = *reinterpret_cast<const float4*>(&xs[l15][ks * 32 + kg * 8 + 4]);
      short2 lv;
      lv.x = f2bf(u0.x);
      lv.y = f2bf(u1.x);
      *reinterpret_cast<short2*>(&al[l15 * S_AL + 8 * ks + 2 * kg]) = lv;
      short4 pv;
      pv.x = f2bf(0.5f * (u0.x + u0.y));
      pv.y = f2bf(0.5f * (u0.z + u0.w));
      pv.z = f2bf(0.5f * (u1.x + u1.y));
      pv.w = f2bf(0.5f * (u1.z + u1.w));
      *reinterpret_cast<short4*>(&pl[l15 * S_PL + ks * 16 + kg * 4]) = pv;
      const bf16x8 a = { lv.x, f2bf(u0.y), f2bf(u0.z), f2bf(u0.w),
                         lv.y, f2bf(u1.y), f2bf(u1.z), f2bf(u1.w) };
      bf16x8 b;
      if constexpr (USE_WS) {
        b = gbv[i];
      } else {
#pragma unroll
        for (int j = 0; j < 8; ++j) b[j] = f2bf(w_g1[(ks * 32 + kg * 8 + j) * HID_ + l15]);
      }
      accg = __builtin_amdgcn_mfma_f32_16x16x32_bf16(a, b, accg, 0, 0, 0);
    }
#pragma unroll
    for (int r = 0; r < 4; ++r) red2[wv][kg * 4 + r][l15] = accg[r];

    __syncthreads();   // B1: xs consumed; al/pl/red2 visible

    // ---- stage next tile into the SAME xs buffer (xs is dead until next gate) ----
    if (t + 1 < TPB) stage(t + 1);

    // ---- local A fragments from al ----
    bf16x8 aL[KT_L];
#pragma unroll
    for (int ks = 0; ks < KT_L; ++ks)
      aL[ks] = *reinterpret_cast<const bf16x8*>(&al[l15 * S_AL + ks * 32 + kg * 8]);

    // ---- issue first two wsL fragment groups (L2), then hide latency under gate finalize ----
    bf16x8 fA[6], fB[6];
    if constexpr (USE_WS) {
#pragma unroll
      for (int j = 0; j < 6; ++j) gload_frag(fA[j], wlp + (j * 6 + 0) * 512);
#pragma unroll
      for (int j = 0; j < 6; ++j) gload_frag(fB[j], wlp + (j * 6 + 1) * 512);
    }

    // ---- gate finalize: combine 4 wave partials, LN over 16, GeLU, dot w_g2 ----
    float gf[4];
#pragma unroll
    for (int r = 0; r < 4; ++r) {
      const int row = kg * 4 + r;
      const float y = red2[0][row][l15] + red2[1][row][l15] +
                      red2[2][row][l15] + red2[3][row][l15] + bg;
      float s = y, q = y * y;
#pragma unroll
      for (int m = 1; m < 16; m <<= 1) {
        s += __shfl_xor(s, m);
        q += __shfl_xor(q, m);
      }
      const float mean = s * (1.f / 16.f);
      const float var  = q * (1.f / 16.f) - mean * mean;
      const float rstd = rsqrtf(var + 1e-5f);
      const float vn = (y - mean) * rstd * lgw + lgb;
      float ps = gelu(vn) * wg2;
#pragma unroll
      for (int m = 1; m < 16; m <<= 1) ps += __shfl_xor(ps, m);
      gf[r] = ps + bg2;
    }

    // ---- local GEMM: counted-vmcnt pipeline (stage loads are oldest; drained by 1st wait) ----
    f32x4 acc[6];
#pragma unroll
    for (int j = 0; j < 6; ++j) acc[j] = (f32x4){0.f, 0.f, 0.f, 0.f};

    if constexpr (USE_WS) {
      WAITV(6);   // stage(t+1) + fA(ks0) done; fB in flight
#pragma unroll
      for (int j = 0; j < 6; ++j)
        acc[j] = __builtin_amdgcn_mfma_f32_16x16x32_bf16(aL[0], fA[j], acc[j], 0, 0, 0);
#pragma unroll
      for (int j = 0; j < 6; ++j) gload_frag(fA[j], wlp + (j * 6 + 2) * 512);
      WAITV(6);
#pragma unroll
      for (int j = 0; j < 6; ++j)
        acc[j] = __builtin_amdgcn_mfma_f32_16x16x32_bf16(aL[1], fB[j], acc[j], 0, 0, 0);
#pragma unroll
      for (int j = 0; j < 6; ++j) gload_frag(fB[j], wlp + (j * 6 + 3) * 512);
      WAITV(6);
#pragma unroll
      for (int j = 0; j < 6; ++j)
        acc[j] = __builtin_amdgcn_mfma_f32_16x16x32_bf16(aL[2], fA[j], acc[j], 0, 0, 0);
#pragma unroll
      for (int j = 0; j < 6; ++j) gload_frag(fA[j], wlp + (j * 6 + 4) * 512);
      WAITV(6);
#pragma unroll
      for (int j = 0; j < 6; ++j)
        acc[j] = __builtin_amdgcn_mfma_f32_16x16x32_bf16(aL[3], fB[j], acc[j], 0, 0, 0);
#pragma unroll
      for (int j = 0; j < 6; ++j) gload_frag(fB[j], wlp + (j * 6 + 5) * 512);
      WAITV(6);
#pragma unroll
      for (int j = 0; j < 6; ++j)
        acc[j] = __builtin_amdgcn_mfma_f32_16x16x32_bf16(aL[4], fA[j], acc[j], 0, 0, 0);
      WAITV(0);
#pragma unroll
      for (int j = 0; j < 6; ++j)
        acc[j] = __builtin_amdgcn_mfma_f32_16x16x32_bf16(aL[5], fB[j], acc[j], 0, 0, 0);
      __builtin_amdgcn_sched_barrier(0);
    } else {
#pragma unroll
      for (int ks = 0; ks < KT_L; ++ks) {
#pragma unroll
        for (int j = 0; j < 6; ++j) {
          const int ng = wv * 6 + j;
          bf16x8 b;
#pragma unroll
          for (int jj = 0; jj < 8; ++jj)
            b[jj] = f2bf(w_l[(ks * 32 + kg * 8 + jj) * OUT_ + ng * 16 + l15]);
          acc[j] = __builtin_amdgcn_mfma_f32_16x16x32_bf16(aL[ks], b, acc[j], 0, 0, 0);
        }
      }
      asm volatile("s_waitcnt vmcnt(0)" ::: "memory");   // ensure stage(t+1) done
      __builtin_amdgcn_sched_barrier(0);
    }

    // ---- add b_l, per-row LN stats over this wave's 96 cols ----
    float s1[4] = {0.f, 0.f, 0.f, 0.f}, s2[4] = {0.f, 0.f, 0.f, 0.f};
#pragma unroll
    for (int j = 0; j < 6; ++j) {
#pragma unroll
      for (int r = 0; r < 4; ++r) {
        const float v = acc[j][r] + blv[j];
        acc[j][r] = v;
        s1[r] += v;
        s2[r] += v * v;
      }
    }
#pragma unroll
    for (int m = 1; m < 16; m <<= 1) {
#pragma unroll
      for (int r = 0; r < 4; ++r) {
        s1[r] += __shfl_xor(s1[r], m);
        s2[r] += __shfl_xor(s2[r], m);
      }
    }
    if (l15 == 0) {
#pragma unroll
      for (int r = 0; r < 4; ++r) {
        reds[wv][kg * 4 + r][0] = s1[r];
        reds[wv][kg * 4 + r][1] = s2[r];
      }
    }
    __syncthreads();   // B2: reds visible (and every wave's stage-confirming wait done)

    // ---- local finalize: LN over 384 (4-wave combine), GeLU, + pooled + gate; store ----
    float meanr[4], rstdr[4];
#pragma unroll
    for (int r = 0; r < 4; ++r) {
      const int row = kg * 4 + r;
      const float t1 = reds[0][row][0] + reds[1][row][0] + reds[2][row][0] + reds[3][row][0];
      const float t2 = reds[0][row][1] + reds[1][row][1] + reds[2][row][1] + reds[3][row][1];
      meanr[r] = t1 * (1.f / 384.f);
      const float var = t2 * (1.f / 384.f) - meanr[r] * meanr[r];
      rstdr[r] = rsqrtf(var + 1e-5f);
    }
#pragma unroll
    for (int j = 0; j < 6; ++j) {
      const int col = (wv * 6 + j) * 16 + l15;
#pragma unroll
      for (int r = 0; r < 4; ++r) {
        const int row = kg * 4 + r;
        const float pooled = bf2f(pl[row * S_PL + col]);
        const float vn = (acc[j][r] - meanr[r]) * rstdr[r] * lwv[j] + lbv[j];
        out[(rowg0 + row) * OUT_ + col] = gelu(vn) + gf[r] + pooled;
      }
    }
    __syncthreads();   // B3: al/pl consumed; next tile's gate may overwrite them
  }
}

// ---------------- launch ----------------
extern "C" void kernel_launch(void* const* d_in, const int* in_sizes, int n_in,
                              void* d_out, int out_size, void* d_ws, size_t ws_size,
                              hipStream_t stream) {
  (void)in_sizes; (void)n_in; (void)out_size;
  const float* x      = (const float*)d_in[0];
  const float* w_g1   = (const float*)d_in[1];
  const float* b_g1   = (const float*)d_in[2];
  const float* ln_g_w = (const float*)d_in[3];
  const float* ln_g_b = (const float*)d_in[4];
  const float* w_g2   = (const float*)d_in[5];
  const float* b_g2   = (const float*)d_in[6];
  const float* w_l    = (const float*)d_in[7];
  const float* b_l    = (const float*)d_in[8];
  const float* ln_l_w = (const float*)d_in[9];
  const float* ln_l_b = (const float*)d_in[10];
  float* out = (float*)d_out;

  const size_t needL = (size_t)NT * KT_L * 64 * 8;   // shorts
  const size_t needG = (size_t)KT_G * 64 * 8;        // shorts
  const bool use_ws = ws_size >= (needL + needG) * sizeof(short);

  short* wsL = (short*)d_ws;
  short* wsG = wsL + needL;

  const int grid = ROWS / (TILE_M * TPB);   // 512
  if (use_ws) {
    prep_kernel<<<(NT * KT_L + KT_G) * 64 / 256, 256, 0, stream>>>(w_l, w_g1, wsL, wsG);
    spectre_kernel<true><<<grid, 256, 0, stream>>>(x, w_g1, b_g1, ln_g_w, ln_g_b, w_g2, b_g2,
                                                   w_l, b_l, ln_l_w, ln_l_b, wsL, wsG, out);
  } else {
    spectre_kernel<false><<<grid, 256, 0, stream>>>(x, w_g1, b_g1, ln_g_w, ln_g_b, w_g2, b_g2,
                                                    w_l, b_l, ln_l_w, ln_l_b, nullptr, nullptr, out);
  }
}